// Round 1
// baseline (624.898 us; speedup 1.0000x reference)
//
#include <hip/hip_runtime.h>
#include <cstddef>

// Problem constants (match reference)
#define B_TOT   4096
#define N_PTS   64
#define D_DIM   256
#define OUT_DIM 512
#define LN_EPS    1e-5f
#define NORM_EPS  1e-12f

// ---------------------------------------------------------------------------
// wave-wide (64-lane) reductions
// ---------------------------------------------------------------------------
__device__ __forceinline__ float wsum64(float v) {
#pragma unroll
  for (int m = 32; m >= 1; m >>= 1) v += __shfl_xor(v, m, 64);
  return v;
}
__device__ __forceinline__ float wmax64(float v) {
#pragma unroll
  for (int m = 32; m >= 1; m >>= 1) v = fmaxf(v, __shfl_xor(v, m, 64));
  return v;
}

// ---------------------------------------------------------------------------
// Kernel 0: transpose w1 [512,256] -> w1t [256,512] and w2 [512,512] -> w2t
// into workspace, so the MLP kernel reads weights coalesced.
// Grid: 384 blocks (128 tiles for w1, 256 for w2), 256 threads.
// ---------------------------------------------------------------------------
__global__ __launch_bounds__(256) void transpose_ws(
    const float* __restrict__ w1, const float* __restrict__ w2,
    float* __restrict__ ws) {
  float* w1t = ws;
  float* w2t = ws + D_DIM * OUT_DIM;
  __shared__ float tile[32][33];  // +1 pad: no bank conflicts on transpose read
  const int bid = blockIdx.x;
  const float* src; float* dst; int R, C, tb;
  if (bid < 128) { src = w1; dst = w1t; R = OUT_DIM; C = D_DIM;  tb = bid; }
  else           { src = w2; dst = w2t; R = OUT_DIM; C = OUT_DIM; tb = bid - 128; }
  const int tilesC = C >> 5;
  const int tr = tb / tilesC;
  const int tc = tb % tilesC;
  const int lx = threadIdx.x & 31;
  const int ly = threadIdx.x >> 5;  // 0..7
#pragma unroll
  for (int k = 0; k < 4; ++k)
    tile[ly + 8 * k][lx] = src[(size_t)(tr * 32 + ly + 8 * k) * C + tc * 32 + lx];
  __syncthreads();
#pragma unroll
  for (int k = 0; k < 4; ++k)
    dst[(size_t)(tc * 32 + ly + 8 * k) * R + tr * 32 + lx] = tile[lx][ly + 8 * k];
}

// ---------------------------------------------------------------------------
// Kernel 1: soft clustering iterations. One block per batch element b.
// 256 threads = 4 waves. h[b] (64x256 f32 = 64 KB) staged once in LDS;
// all 3 iterations run from LDS + registers. Thread t owns dimension t of mu.
// Writes alpha [B,64] and mu [B,256] regions of d_out.
// ---------------------------------------------------------------------------
__global__ __launch_bounds__(256) void ica_cluster(
    const float* __restrict__ h, const float* __restrict__ log_tau,
    float* __restrict__ alpha_out, float* __restrict__ mu_out) {
  __shared__ float hs[N_PTS * D_DIM];  // 64 KB, row-major [n][d]
  __shared__ float mun[D_DIM];         // normalized mu (scaled by 1/tau)
  __shared__ float siml[N_PTS];
  __shared__ float rinv[N_PTS];        // 1/max(||h[n]||, eps)
  __shared__ float redp[4];            // cross-wave reduction partials

  const int t = threadIdx.x;
  const int lane = t & 63;
  const int w = t >> 6;
  const int b = blockIdx.x;

  // ---- stage h[b] into LDS (float4, fully coalesced: 1 KB per wave-instr)
  float4* hs4 = (float4*)hs;
  const float4* hg = (const float4*)h + (size_t)b * (N_PTS * D_DIM / 4);
#pragma unroll
  for (int k = 0; k < 16; ++k) hs4[t + 256 * k] = hg[t + 256 * k];

  float tau = expf(log_tau[0]);
  tau = fminf(fmaxf(tau, 0.01f), 2.0f);
  const float inv_tau = 1.0f / tau;
  __syncthreads();

  // ---- per-row inverse norms: wave w handles rows w*16 .. w*16+15
#pragma unroll
  for (int j = 0; j < 16; ++j) {
    const int n = w * 16 + j;
    const float4 a = hs4[n * 64 + lane];
    float ss = a.x * a.x + a.y * a.y + a.z * a.z + a.w * a.w;
    ss = wsum64(ss);
    if (lane == 0) rinv[n] = 1.0f / fmaxf(sqrtf(ss), NORM_EPS);
  }

  // ---- initial mu = mean over n (thread t owns dim t; column reads coalesced)
  float mu = 0.0f;
#pragma unroll 8
  for (int n = 0; n < N_PTS; ++n) mu += hs[n * D_DIM + t];
  mu *= (1.0f / 64.0f);

  float alpha = 1.0f / 64.0f;

  for (int it = 0; it < 3; ++it) {
    // ||mu||^2 : wave-reduce then cross-wave via LDS
    float p = wsum64(mu * mu);
    if (lane == 0) redp[w] = p;
    __syncthreads();
    const float n2 = redp[0] + redp[1] + redp[2] + redp[3];
    const float sc = inv_tau / fmaxf(sqrtf(n2), NORM_EPS);  // fold 1/tau into mu_n
    mun[t] = mu * sc;
    __syncthreads();

    // sim[n] = (h[n] . mu_n) * rinv[n]   (already has the /tau folded in)
    const float4 mm = ((const float4*)mun)[lane];
#pragma unroll
    for (int j = 0; j < 16; ++j) {
      const int n = w * 16 + j;
      const float4 a = hs4[n * 64 + lane];
      float pp = a.x * mm.x + a.y * mm.y + a.z * mm.z + a.w * mm.w;
      pp = wsum64(pp);
      if (lane == 0) siml[n] = pp * rinv[n];
    }
    __syncthreads();

    // softmax over 64 rows — each wave computes it redundantly (no barrier)
    const float v = siml[lane];
    const float mx = wmax64(v);
    const float e = expf(v - mx);
    const float s = wsum64(e);
    alpha = e / s;

    // mu[t] = sum_n alpha[n] * h[n][t]  (readlane broadcast + coalesced LDS col)
    float nm = 0.0f;
#pragma unroll 8
    for (int n = 0; n < N_PTS; ++n)
      nm = fmaf(__shfl(alpha, n, 64), hs[n * D_DIM + t], nm);
    mu = nm;
    // no trailing barrier needed: next write to redp/mun/siml is separated from
    // this iteration's reads by >=1 barrier in program order.
  }

  if (w == 0) alpha_out[(size_t)b * N_PTS + lane] = alpha;
  mu_out[(size_t)b * D_DIM + t] = mu;
}

// ---------------------------------------------------------------------------
// Kernel 2: rho MLP.  theta = LN(GELU(LN(mu@w1^T+b1))@w2^T + b2)
// One block per 16 batch rows; 512 threads, thread t owns output column t.
// Weights read pre-transposed (coalesced), each element reused 16x.
// ---------------------------------------------------------------------------
__global__ __launch_bounds__(512) void ica_mlp(
    const float* __restrict__ mu_in, const float* __restrict__ w1t,
    const float* __restrict__ b1, const float* __restrict__ g1,
    const float* __restrict__ be1, const float* __restrict__ w2t,
    const float* __restrict__ b2, const float* __restrict__ g2,
    const float* __restrict__ be2, float* __restrict__ theta) {
  __shared__ float ml[16 * D_DIM];    // 16 KB: 16 rows of mu
  __shared__ float xl[16 * OUT_DIM];  // 32 KB: intermediate activations
  const int t = threadIdx.x;
  const int lane = t & 63;
  const int w = t >> 6;  // 0..7
  const int b0 = blockIdx.x * 16;

  // stage 16 mu rows
  float4* ml4 = (float4*)ml;
  const float4* mg = (const float4*)(mu_in + (size_t)b0 * D_DIM);
  ml4[t] = mg[t];
  ml4[t + 512] = mg[t + 512];
  __syncthreads();

  // ---- layer 1: acc[r] = b1[t] + sum_i mu[r][i] * w1t[i][t]
  float acc[16];
  {
    const float bb = b1[t];
#pragma unroll
    for (int r = 0; r < 16; ++r) acc[r] = bb;
  }
  const float4* ml4c = (const float4*)ml;
  for (int i = 0; i < D_DIM; i += 4) {
    const float wv0 = w1t[(size_t)(i + 0) * OUT_DIM + t];
    const float wv1 = w1t[(size_t)(i + 1) * OUT_DIM + t];
    const float wv2 = w1t[(size_t)(i + 2) * OUT_DIM + t];
    const float wv3 = w1t[(size_t)(i + 3) * OUT_DIM + t];
#pragma unroll
    for (int r = 0; r < 16; ++r) {
      const float4 m = ml4c[r * 64 + (i >> 2)];  // LDS broadcast
      float a = acc[r];
      a = fmaf(m.x, wv0, a);
      a = fmaf(m.y, wv1, a);
      a = fmaf(m.z, wv2, a);
      a = fmaf(m.w, wv3, a);
      acc[r] = a;
    }
  }
#pragma unroll
  for (int r = 0; r < 16; ++r) xl[r * OUT_DIM + t] = acc[r];
  __syncthreads();

  // ---- LN1 + exact GELU; 8 waves x 2 rows each
#pragma unroll
  for (int q = 0; q < 2; ++q) {
    const int r = w + 8 * q;
    float v[8];
#pragma unroll
    for (int k = 0; k < 8; ++k) v[k] = xl[r * OUT_DIM + lane + 64 * k];
    float s = 0.f;
#pragma unroll
    for (int k = 0; k < 8; ++k) s += v[k];
    s = wsum64(s);
    const float mean = s * (1.0f / 512.0f);
    float vs = 0.f;
#pragma unroll
    for (int k = 0; k < 8; ++k) { const float d = v[k] - mean; vs += d * d; }
    vs = wsum64(vs);
    const float rstd = 1.0f / sqrtf(vs * (1.0f / 512.0f) + LN_EPS);
#pragma unroll
    for (int k = 0; k < 8; ++k) {
      const int j = lane + 64 * k;
      const float y = (v[k] - mean) * rstd * g1[j] + be1[j];
      const float ge = 0.5f * y * (1.0f + erff(y * 0.70710678118654752f));
      xl[r * OUT_DIM + j] = ge;
    }
  }
  __syncthreads();

  // ---- layer 2
  float acc2[16];
  {
    const float bb = b2[t];
#pragma unroll
    for (int r = 0; r < 16; ++r) acc2[r] = bb;
  }
  const float4* xl4 = (const float4*)xl;
  for (int i = 0; i < OUT_DIM; i += 4) {
    const float wv0 = w2t[(size_t)(i + 0) * OUT_DIM + t];
    const float wv1 = w2t[(size_t)(i + 1) * OUT_DIM + t];
    const float wv2 = w2t[(size_t)(i + 2) * OUT_DIM + t];
    const float wv3 = w2t[(size_t)(i + 3) * OUT_DIM + t];
#pragma unroll
    for (int r = 0; r < 16; ++r) {
      const float4 x = xl4[r * 128 + (i >> 2)];
      float a = acc2[r];
      a = fmaf(x.x, wv0, a);
      a = fmaf(x.y, wv1, a);
      a = fmaf(x.z, wv2, a);
      a = fmaf(x.w, wv3, a);
      acc2[r] = a;
    }
  }
  __syncthreads();  // xl fully consumed before overwrite
#pragma unroll
  for (int r = 0; r < 16; ++r) xl[r * OUT_DIM + t] = acc2[r];
  __syncthreads();

  // ---- LN2 + store theta
#pragma unroll
  for (int q = 0; q < 2; ++q) {
    const int r = w + 8 * q;
    float v[8];
#pragma unroll
    for (int k = 0; k < 8; ++k) v[k] = xl[r * OUT_DIM + lane + 64 * k];
    float s = 0.f;
#pragma unroll
    for (int k = 0; k < 8; ++k) s += v[k];
    s = wsum64(s);
    const float mean = s * (1.0f / 512.0f);
    float vs = 0.f;
#pragma unroll
    for (int k = 0; k < 8; ++k) { const float d = v[k] - mean; vs += d * d; }
    vs = wsum64(vs);
    const float rstd = 1.0f / sqrtf(vs * (1.0f / 512.0f) + LN_EPS);
#pragma unroll
    for (int k = 0; k < 8; ++k) {
      const int j = lane + 64 * k;
      theta[(size_t)(b0 + r) * OUT_DIM + j] = (v[k] - mean) * rstd * g2[j] + be2[j];
    }
  }
}

// ---------------------------------------------------------------------------
extern "C" void kernel_launch(void* const* d_in, const int* in_sizes, int n_in,
                              void* d_out, int out_size, void* d_ws, size_t ws_size,
                              hipStream_t stream) {
  const float* h       = (const float*)d_in[0];
  const float* log_tau = (const float*)d_in[1];
  const float* w1      = (const float*)d_in[2];
  const float* b1      = (const float*)d_in[3];
  const float* g1      = (const float*)d_in[4];
  const float* be1     = (const float*)d_in[5];
  const float* w2      = (const float*)d_in[6];
  const float* b2      = (const float*)d_in[7];
  const float* g2      = (const float*)d_in[8];
  const float* be2     = (const float*)d_in[9];

  float* out   = (float*)d_out;
  float* theta = out;                                   // [B, 512]
  float* alpha = out + (size_t)B_TOT * OUT_DIM;         // [B, 64]
  float* mu    = alpha + (size_t)B_TOT * N_PTS;         // [B, 256]

  float* ws  = (float*)d_ws;
  float* w1t = ws;                       // [256, 512]
  float* w2t = ws + D_DIM * OUT_DIM;     // [512, 512]

  transpose_ws<<<384, 256, 0, stream>>>(w1, w2, ws);
  ica_cluster<<<B_TOT, 256, 0, stream>>>(h, log_tau, alpha, mu);
  ica_mlp<<<B_TOT / 16, 512, 0, stream>>>(mu, w1t, b1, g1, be1,
                                          w2t, b2, g2, be2, theta);
}

// Round 4
// 558.566 us; speedup vs baseline: 1.1188x; 1.1188x over previous
//
#include <hip/hip_runtime.h>
#include <cstddef>

#define B_TOT   4096
#define N_PTS   64
#define D_DIM   256
#define OUT_DIM 512
#define LN_EPS    1e-5f
#define NORM_EPS  1e-12f

// ---------------------------------------------------------------------------
// Wave64 reductions on the VALU pipe via DPP (no LDS/ds_swizzle traffic).
// Sequence: row_shr 1,2,4,8 then row_bcast15, row_bcast31 -> total in lane 63.
// ---------------------------------------------------------------------------
template <int CTRL>
__device__ __forceinline__ float dpp_add_step(float x) {
  const int r = __builtin_amdgcn_update_dpp(0, __float_as_int(x), CTRL, 0xF, 0xF, true);
  return x + __int_as_float(r);
}
__device__ __forceinline__ float dpp_sum64(float x) {  // total valid in lane 63
  x = dpp_add_step<0x111>(x);
  x = dpp_add_step<0x112>(x);
  x = dpp_add_step<0x114>(x);
  x = dpp_add_step<0x118>(x);
  x = dpp_add_step<0x142>(x);
  x = dpp_add_step<0x143>(x);
  return x;
}
template <int CTRL>
__device__ __forceinline__ float dpp_max_step(float x) {
  const int xi = __float_as_int(x);
  const int r = __builtin_amdgcn_update_dpp(xi, xi, CTRL, 0xF, 0xF, false);
  return fmaxf(x, __int_as_float(r));
}
__device__ __forceinline__ float dpp_max64(float x) {  // max valid in lane 63
  x = dpp_max_step<0x111>(x);
  x = dpp_max_step<0x112>(x);
  x = dpp_max_step<0x114>(x);
  x = dpp_max_step<0x118>(x);
  x = dpp_max_step<0x142>(x);
  x = dpp_max_step<0x143>(x);
  return x;
}
__device__ __forceinline__ float rdlane(float x, int sl) {
  return __int_as_float(__builtin_amdgcn_readlane(__float_as_int(x), sl));
}
__device__ __forceinline__ float bsum64(float x) { return rdlane(dpp_sum64(x), 63); }
__device__ __forceinline__ float bmax64(float x) { return rdlane(dpp_max64(x), 63); }

// ---------------------------------------------------------------------------
// Kernel 0: pack weights into float4-contiguous layout:
// wXp[k][c][0..3] = wX[c][4k+0..3]  (k = i/4). MLP then loads one coalesced
// float4 of weights per column per k-step.
// ---------------------------------------------------------------------------
__global__ __launch_bounds__(256) void pack_weights(
    const float* __restrict__ w1, const float* __restrict__ w2,
    float* __restrict__ w1p, float* __restrict__ w2p) {
  const int idx = blockIdx.x * 256 + threadIdx.x;
  if (idx < OUT_DIM * D_DIM) {
    const int c = idx >> 8;        // w1 output row (0..511)
    const int i = idx & 255;       // k index (0..255)
    w1p[((size_t)(i >> 2) << 11) + (c << 2) + (i & 3)] = w1[idx];
  }
  if (idx < OUT_DIM * OUT_DIM) {
    const int c = idx >> 9;
    const int i = idx & 511;
    w2p[((size_t)(i >> 2) << 11) + (c << 2) + (i & 3)] = w2[idx];
  }
}

// ---------------------------------------------------------------------------
// Kernel 1: soft clustering. One block (1024 thr = 16 waves) per batch b.
// h[b] staged+row-normalized in LDS once (row norms folded into the alpha
// weights). All reductions via DPP; alpha broadcast via v_readlane (SGPR idx).
// mu lives as float4 in wave 0; column sums use a 2-round LDS combine.
// LDS ~73.6 KB -> 2 blocks/CU; launch_bounds(1024,8) caps VGPR<=64 so the
// VGPR occupancy step (m69: halves at 64) doesn't undercut the LDS limit.
// ---------------------------------------------------------------------------
__global__ __launch_bounds__(1024, 8) void ica_cluster(
    const float* __restrict__ h, const float* __restrict__ log_tau,
    float* __restrict__ alpha_out, float* __restrict__ mu_out) {
  __shared__ float  hs[N_PTS * D_DIM];   // 64 KB, row-normalized after setup
  __shared__ float4 musum4[8 * 64];      // 8 KB partial column sums
  __shared__ float4 mun4[64];            // normalized mu * (1/tau)
  __shared__ float  siml[N_PTS];
  __shared__ float  hnormS[N_PTS];

  const int t = threadIdx.x;
  const int lane = t & 63;
  const int w = t >> 6;                  // 0..15
  const int b = blockIdx.x;

  float4* hs4 = (float4*)hs;
  const float4* hg = (const float4*)(h + (size_t)b * (N_PTS * D_DIM));
#pragma unroll
  for (int k = 0; k < 4; ++k) hs4[t + 1024 * k] = hg[t + 1024 * k];

  float tau = expf(log_tau[0]);
  tau = fminf(fmaxf(tau, 0.01f), 2.0f);
  const float inv_tau = 1.0f / tau;
  __syncthreads();

  // ---- normalize rows in place; keep norms (wave w owns rows 4w..4w+3)
#pragma unroll
  for (int j = 0; j < 4; ++j) {
    const int n = (w << 2) + j;
    float4 a = hs4[n * 64 + lane];
    float ss = fmaf(a.x, a.x, fmaf(a.y, a.y, fmaf(a.z, a.z, a.w * a.w)));
    ss = bsum64(ss);
    const float nr = sqrtf(ss);
    const float inv = 1.0f / fmaxf(nr, NORM_EPS);
    a.x *= inv; a.y *= inv; a.z *= inv; a.w *= inv;
    hs4[n * 64 + lane] = a;
    if (lane == 63) hnormS[n] = nr;
  }
  __syncthreads();
  const float hnorm_l = hnormS[lane];                        // norm of row `lane`
  const int sbase = __builtin_amdgcn_readfirstlane(w) << 2;  // wave's first row

  // weighted column sum: weight for row n taken from lane n of `wgt`.
  // Result (full mu as float4-per-lane) valid in wave 0 only.
  auto col_wsum = [&](float wgt) -> float4 {
    float4 nm = {0.f, 0.f, 0.f, 0.f};
#pragma unroll
    for (int j = 0; j < 4; ++j) {
      const float a = rdlane(wgt, sbase + j);                // SGPR broadcast
      const float4 hv = hs4[(sbase + j) * 64 + lane];
      nm.x = fmaf(a, hv.x, nm.x);
      nm.y = fmaf(a, hv.y, nm.y);
      nm.z = fmaf(a, hv.z, nm.z);
      nm.w = fmaf(a, hv.w, nm.w);
    }
    if (w >= 8) musum4[((w - 8) << 6) + lane] = nm;
    __syncthreads();
    if (w < 8) {
      float4 o = musum4[(w << 6) + lane];
      o.x += nm.x; o.y += nm.y; o.z += nm.z; o.w += nm.w;
      musum4[(w << 6) + lane] = o;
    }
    __syncthreads();
    float4 mu = {0.f, 0.f, 0.f, 0.f};
    if (w == 0) {
#pragma unroll
      for (int s = 0; s < 8; ++s) {
        const float4 p = musum4[(s << 6) + lane];
        mu.x += p.x; mu.y += p.y; mu.z += p.z; mu.w += p.w;
      }
    }
    return mu;
  };

  // initial mu = mean over rows = sum(norm_n/64 * hhat_n)
  float4 mu4 = col_wsum(hnorm_l * (1.0f / 64.0f));

  float alpha = 0.f;
  for (int it = 0; it < 3; ++it) {
    // ---- normalize mu (wave 0 only), fold in 1/tau
    if (w == 0) {
      float ss = fmaf(mu4.x, mu4.x, fmaf(mu4.y, mu4.y, fmaf(mu4.z, mu4.z, mu4.w * mu4.w)));
      ss = bsum64(ss);
      const float sc = inv_tau / fmaxf(sqrtf(ss), NORM_EPS);
      float4 m;
      m.x = mu4.x * sc; m.y = mu4.y * sc; m.z = mu4.z * sc; m.w = mu4.w * sc;
      mun4[lane] = m;
    }
    __syncthreads();

    // ---- sim[n] = hhat[n] . (muhat/tau)   (wave w: rows 4w..4w+3)
    const float4 mm = mun4[lane];
#pragma unroll
    for (int j = 0; j < 4; ++j) {
      const int n = (w << 2) + j;
      const float4 a = hs4[n * 64 + lane];
      float pp = fmaf(a.x, mm.x, fmaf(a.y, mm.y, fmaf(a.z, mm.z, a.w * mm.w)));
      pp = dpp_sum64(pp);
      if (lane == 63) siml[n] = pp;
    }
    __syncthreads();

    // ---- softmax over 64 (redundant per wave; lane holds alpha[lane])
    const float v = siml[lane];
    const float mx = bmax64(v);
    const float e = expf(v - mx);
    const float s = bsum64(e);
    alpha = e / s;

    // ---- mu = sum_n alpha[n] * h[n] = sum_n (alpha*norm)[n] * hhat[n]
    mu4 = col_wsum(alpha * hnorm_l);
  }

  if (t < N_PTS) alpha_out[(size_t)b * N_PTS + t] = alpha;
  if (w == 0) ((float4*)(mu_out + (size_t)b * D_DIM))[lane] = mu4;
}

// ---------------------------------------------------------------------------
// Kernel 2: rho MLP, row-in-lane tiling. 512 thr (8 waves), 8 batch rows per
// block, grid 512 (2 blocks/CU). Lane l owns row l>>3 and cols
// 64*w + (l&7) + 8j (j=0..7). Activations: ONE padded conflict-free
// ds_read_b128 per k-step (8 distinct rows across the wave); weights: packed
// float4, duplicate lanes coalesce to 128B/instr. LN reductions via DPP.
// ---------------------------------------------------------------------------
#define ML_PAD 260   // 256 + 4 floats: rows hit distinct banks (stride 4 mod 32)
#define XL_PAD 516   // 512 + 4 floats

__global__ __launch_bounds__(512, 4) void ica_mlp(
    const float* __restrict__ mu_in, const float* __restrict__ w1p,
    const float* __restrict__ b1, const float* __restrict__ g1,
    const float* __restrict__ be1, const float* __restrict__ w2p,
    const float* __restrict__ b2, const float* __restrict__ g2,
    const float* __restrict__ be2, float* __restrict__ theta) {
  __shared__ float ml[8 * ML_PAD];   // 8.3 KB
  __shared__ float xl[8 * XL_PAD];   // 16.5 KB
  const int t = threadIdx.x;
  const int lane = t & 63;
  const int w = t >> 6;                    // 0..7
  const int b0 = blockIdx.x * 8;
  const int r = lane >> 3;                 // owned row 0..7
  const int cb = (w << 6) + (lane & 7);    // column base; cols cb+8j

  // stage 8 mu rows into padded LDS (thread t: row t>>6, float4-col t&63)
  {
    const int sr = t >> 6;
    const int sc = t & 63;
    const float4 v = ((const float4*)(mu_in + (size_t)(b0 + sr) * D_DIM))[sc];
    *((float4*)(ml + sr * ML_PAD) + sc) = v;
  }
  __syncthreads();

  // ---- layer 1: x = mu @ w1^T + b1
  float acc[8];
#pragma unroll
  for (int j = 0; j < 8; ++j) acc[j] = b1[cb + 8 * j];
  {
    const float4* wp = (const float4*)w1p;            // [64][512] float4
    const float4* mlr = (const float4*)(ml + r * ML_PAD);
    for (int k = 0; k < 64; ++k) {
      const float4 m = mlr[k];                        // 1 ds_read_b128 / wave
#pragma unroll
      for (int j = 0; j < 8; ++j) {
        const float4 wv = wp[(size_t)k * OUT_DIM + cb + 8 * j];
        acc[j] = fmaf(m.x, wv.x, acc[j]);
        acc[j] = fmaf(m.y, wv.y, acc[j]);
        acc[j] = fmaf(m.z, wv.z, acc[j]);
        acc[j] = fmaf(m.w, wv.w, acc[j]);
      }
    }
  }
#pragma unroll
  for (int j = 0; j < 8; ++j) xl[r * XL_PAD + cb + 8 * j] = acc[j];
  __syncthreads();

  // ---- LN1 + exact GELU (wave w -> row w)
  {
    float v[8];
#pragma unroll
    for (int kk = 0; kk < 8; ++kk) v[kk] = xl[w * XL_PAD + lane + 64 * kk];
    float s = 0.f;
#pragma unroll
    for (int kk = 0; kk < 8; ++kk) s += v[kk];
    const float mean = bsum64(s) * (1.0f / 512.0f);
    float vs = 0.f;
#pragma unroll
    for (int kk = 0; kk < 8; ++kk) { const float d = v[kk] - mean; vs = fmaf(d, d, vs); }
    const float rstd = 1.0f / sqrtf(bsum64(vs) * (1.0f / 512.0f) + LN_EPS);
#pragma unroll
    for (int kk = 0; kk < 8; ++kk) {
      const int jx = lane + 64 * kk;
      const float y = (v[kk] - mean) * rstd * g1[jx] + be1[jx];
      xl[w * XL_PAD + jx] = 0.5f * y * (1.0f + erff(y * 0.70710678118654752f));
    }
  }
  __syncthreads();

  // ---- layer 2: x @ w2^T + b2
  float acc2[8];
#pragma unroll
  for (int j = 0; j < 8; ++j) acc2[j] = b2[cb + 8 * j];
  {
    const float4* wp = (const float4*)w2p;            // [128][512] float4
    const float4* xlr = (const float4*)(xl + r * XL_PAD);
    for (int k = 0; k < 128; ++k) {
      const float4 m = xlr[k];
#pragma unroll
      for (int j = 0; j < 8; ++j) {
        const float4 wv = wp[(size_t)k * OUT_DIM + cb + 8 * j];
        acc2[j] = fmaf(m.x, wv.x, acc2[j]);
        acc2[j] = fmaf(m.y, wv.y, acc2[j]);
        acc2[j] = fmaf(m.z, wv.z, acc2[j]);
        acc2[j] = fmaf(m.w, wv.w, acc2[j]);
      }
    }
  }
  __syncthreads();   // all xl reads complete before overwrite
#pragma unroll
  for (int j = 0; j < 8; ++j) xl[r * XL_PAD + cb + 8 * j] = acc2[j];
  __syncthreads();

  // ---- LN2 + store theta (wave w -> row w)
  {
    float v[8];
#pragma unroll
    for (int kk = 0; kk < 8; ++kk) v[kk] = xl[w * XL_PAD + lane + 64 * kk];
    float s = 0.f;
#pragma unroll
    for (int kk = 0; kk < 8; ++kk) s += v[kk];
    const float mean = bsum64(s) * (1.0f / 512.0f);
    float vs = 0.f;
#pragma unroll
    for (int kk = 0; kk < 8; ++kk) { const float d = v[kk] - mean; vs = fmaf(d, d, vs); }
    const float rstd = 1.0f / sqrtf(bsum64(vs) * (1.0f / 512.0f) + LN_EPS);
#pragma unroll
    for (int kk = 0; kk < 8; ++kk) {
      const int jx = lane + 64 * kk;
      theta[(size_t)(b0 + w) * OUT_DIM + jx] = (v[kk] - mean) * rstd * g2[jx] + be2[jx];
    }
  }
}

// ---------------------------------------------------------------------------
extern "C" void kernel_launch(void* const* d_in, const int* in_sizes, int n_in,
                              void* d_out, int out_size, void* d_ws, size_t ws_size,
                              hipStream_t stream) {
  const float* h       = (const float*)d_in[0];
  const float* log_tau = (const float*)d_in[1];
  const float* w1      = (const float*)d_in[2];
  const float* b1      = (const float*)d_in[3];
  const float* g1      = (const float*)d_in[4];
  const float* be1     = (const float*)d_in[5];
  const float* w2      = (const float*)d_in[6];
  const float* b2      = (const float*)d_in[7];
  const float* g2      = (const float*)d_in[8];
  const float* be2     = (const float*)d_in[9];

  float* out   = (float*)d_out;
  float* theta = out;                                 // [B, 512]
  float* alpha = out + (size_t)B_TOT * OUT_DIM;       // [B, 64]
  float* mu    = alpha + (size_t)B_TOT * N_PTS;       // [B, 256]

  float* ws  = (float*)d_ws;
  float* w1p = ws;                                    // 64*512 float4
  float* w2p = ws + (size_t)D_DIM * OUT_DIM;          // 128*512 float4

  pack_weights<<<1024, 256, 0, stream>>>(w1, w2, w1p, w2p);
  ica_cluster<<<B_TOT, 1024, 0, stream>>>(h, log_tau, alpha, mu);
  ica_mlp<<<B_TOT / 8, 512, 0, stream>>>(mu, w1p, b1, g1, be1,
                                         w2p, b2, g2, be2, theta);
}

// Round 5
// 418.690 us; speedup vs baseline: 1.4925x; 1.3341x over previous
//
#include <hip/hip_runtime.h>
#include <cstddef>

#define B_TOT   4096
#define N_PTS   64
#define D_DIM   256
#define OUT_DIM 512
#define LN_EPS    1e-5f
#define NORM_EPS  1e-12f

typedef __attribute__((ext_vector_type(8))) short  short8;   // 8 bf16 = 4 VGPRs
typedef __attribute__((ext_vector_type(4))) float  f32x4;

// ---------------------------------------------------------------------------
// Wave64 reductions on the VALU pipe via DPP.
// row_shr 1,2,4,8 then row_bcast15, row_bcast31 -> total in lane 63.
// ---------------------------------------------------------------------------
template <int CTRL>
__device__ __forceinline__ float dpp_add_step(float x) {
  const int r = __builtin_amdgcn_update_dpp(0, __float_as_int(x), CTRL, 0xF, 0xF, true);
  return x + __int_as_float(r);
}
__device__ __forceinline__ float dpp_sum64(float x) {
  x = dpp_add_step<0x111>(x);
  x = dpp_add_step<0x112>(x);
  x = dpp_add_step<0x114>(x);
  x = dpp_add_step<0x118>(x);
  x = dpp_add_step<0x142>(x);
  x = dpp_add_step<0x143>(x);
  return x;
}
template <int CTRL>
__device__ __forceinline__ float dpp_max_step(float x) {
  const int xi = __float_as_int(x);
  const int r = __builtin_amdgcn_update_dpp(xi, xi, CTRL, 0xF, 0xF, false);
  return fmaxf(x, __int_as_float(r));
}
__device__ __forceinline__ float dpp_max64(float x) {
  x = dpp_max_step<0x111>(x);
  x = dpp_max_step<0x112>(x);
  x = dpp_max_step<0x114>(x);
  x = dpp_max_step<0x118>(x);
  x = dpp_max_step<0x142>(x);
  x = dpp_max_step<0x143>(x);
  return x;
}
__device__ __forceinline__ float rdlane(float x, int sl) {
  return __int_as_float(__builtin_amdgcn_readlane(__float_as_int(x), sl));
}
__device__ __forceinline__ float bsum64(float x) { return rdlane(dpp_sum64(x), 63); }
__device__ __forceinline__ float bmax64(float x) { return rdlane(dpp_max64(x), 63); }

// ---------------------------------------------------------------------------
// bf16 split helpers (round-to-nearest-even).  x == hi + lo to ~2^-16 rel.
// ---------------------------------------------------------------------------
__device__ __forceinline__ unsigned short bf16_rne(float x) {
  const unsigned u = __float_as_uint(x);
  return (unsigned short)((u + 0x7FFFu + ((u >> 16) & 1u)) >> 16);
}
__device__ __forceinline__ float bf16_tof(unsigned short h) {
  return __uint_as_float(((unsigned)h) << 16);
}
__device__ __forceinline__ void split8(const float4& p, const float4& q,
                                       short8& hi, short8& lo) {
  const float v[8] = {p.x, p.y, p.z, p.w, q.x, q.y, q.z, q.w};
#pragma unroll
  for (int i = 0; i < 8; ++i) {
    const unsigned short h = bf16_rne(v[i]);
    hi[i] = (short)h;
    lo[i] = (short)bf16_rne(v[i] - bf16_tof(h));
  }
}

// ---------------------------------------------------------------------------
// Kernel 0: split weights into hi/lo bf16 and store in MFMA B-fragment order.
// Convention (shared by A-side builder in ica_mlp — any consistent k-slotting
// is correct since HW contracts slot-against-slot):
//   tile nt (16 cols), k-step kk (K=32): lane = ((k>>3)&3)*16 + (col&15),
//   elem i = k&7;  frag idx = ((nt*KSTEPS + kk)*64 + lane)*8 + i.
// ---------------------------------------------------------------------------
__global__ __launch_bounds__(256) void pack_weights(
    const float* __restrict__ w1, const float* __restrict__ w2,
    unsigned short* __restrict__ bh1, unsigned short* __restrict__ bl1,
    unsigned short* __restrict__ bh2, unsigned short* __restrict__ bl2) {
  const int idx = blockIdx.x * 256 + threadIdx.x;
  if (idx < OUT_DIM * D_DIM) {                    // w1 [512][256]
    const int o = idx >> 8, k = idx & 255;
    const float x = w1[idx];
    const unsigned short h = bf16_rne(x);
    const unsigned short l = bf16_rne(x - bf16_tof(h));
    const int lane = ((k >> 3) & 3) * 16 + (o & 15);
    const int fi = (((o >> 4) * 8 + (k >> 5)) * 64 + lane) * 8 + (k & 7);
    bh1[fi] = h; bl1[fi] = l;
  }
  if (idx < OUT_DIM * OUT_DIM) {                  // w2 [512][512]
    const int o = idx >> 9, k = idx & 511;
    const float x = w2[idx];
    const unsigned short h = bf16_rne(x);
    const unsigned short l = bf16_rne(x - bf16_tof(h));
    const int lane = ((k >> 3) & 3) * 16 + (o & 15);
    const int fi = (((o >> 4) * 16 + (k >> 5)) * 64 + lane) * 8 + (k & 7);
    bh2[fi] = h; bl2[fi] = l;
  }
}

// ---------------------------------------------------------------------------
// Kernel 1: soft clustering (UNCHANGED from round-1 design; measured off the
// top-5 this round). One block (1024 thr = 16 waves) per batch b.
// ---------------------------------------------------------------------------
__global__ __launch_bounds__(1024, 8) void ica_cluster(
    const float* __restrict__ h, const float* __restrict__ log_tau,
    float* __restrict__ alpha_out, float* __restrict__ mu_out) {
  __shared__ float  hs[N_PTS * D_DIM];   // 64 KB, row-normalized after setup
  __shared__ float4 musum4[8 * 64];      // 8 KB partial column sums
  __shared__ float4 mun4[64];            // normalized mu * (1/tau)
  __shared__ float  siml[N_PTS];
  __shared__ float  hnormS[N_PTS];

  const int t = threadIdx.x;
  const int lane = t & 63;
  const int w = t >> 6;                  // 0..15
  const int b = blockIdx.x;

  float4* hs4 = (float4*)hs;
  const float4* hg = (const float4*)(h + (size_t)b * (N_PTS * D_DIM));
#pragma unroll
  for (int k = 0; k < 4; ++k) hs4[t + 1024 * k] = hg[t + 1024 * k];

  float tau = expf(log_tau[0]);
  tau = fminf(fmaxf(tau, 0.01f), 2.0f);
  const float inv_tau = 1.0f / tau;
  __syncthreads();

#pragma unroll
  for (int j = 0; j < 4; ++j) {
    const int n = (w << 2) + j;
    float4 a = hs4[n * 64 + lane];
    float ss = fmaf(a.x, a.x, fmaf(a.y, a.y, fmaf(a.z, a.z, a.w * a.w)));
    ss = bsum64(ss);
    const float nr = sqrtf(ss);
    const float inv = 1.0f / fmaxf(nr, NORM_EPS);
    a.x *= inv; a.y *= inv; a.z *= inv; a.w *= inv;
    hs4[n * 64 + lane] = a;
    if (lane == 63) hnormS[n] = nr;
  }
  __syncthreads();
  const float hnorm_l = hnormS[lane];
  const int sbase = __builtin_amdgcn_readfirstlane(w) << 2;

  auto col_wsum = [&](float wgt) -> float4 {
    float4 nm = {0.f, 0.f, 0.f, 0.f};
#pragma unroll
    for (int j = 0; j < 4; ++j) {
      const float a = rdlane(wgt, sbase + j);
      const float4 hv = hs4[(sbase + j) * 64 + lane];
      nm.x = fmaf(a, hv.x, nm.x);
      nm.y = fmaf(a, hv.y, nm.y);
      nm.z = fmaf(a, hv.z, nm.z);
      nm.w = fmaf(a, hv.w, nm.w);
    }
    if (w >= 8) musum4[((w - 8) << 6) + lane] = nm;
    __syncthreads();
    if (w < 8) {
      float4 o = musum4[(w << 6) + lane];
      o.x += nm.x; o.y += nm.y; o.z += nm.z; o.w += nm.w;
      musum4[(w << 6) + lane] = o;
    }
    __syncthreads();
    float4 mu = {0.f, 0.f, 0.f, 0.f};
    if (w == 0) {
#pragma unroll
      for (int s = 0; s < 8; ++s) {
        const float4 p = musum4[(s << 6) + lane];
        mu.x += p.x; mu.y += p.y; mu.z += p.z; mu.w += p.w;
      }
    }
    return mu;
  };

  float4 mu4 = col_wsum(hnorm_l * (1.0f / 64.0f));

  float alpha = 0.f;
  for (int it = 0; it < 3; ++it) {
    if (w == 0) {
      float ss = fmaf(mu4.x, mu4.x, fmaf(mu4.y, mu4.y, fmaf(mu4.z, mu4.z, mu4.w * mu4.w)));
      ss = bsum64(ss);
      const float sc = inv_tau / fmaxf(sqrtf(ss), NORM_EPS);
      float4 m;
      m.x = mu4.x * sc; m.y = mu4.y * sc; m.z = mu4.z * sc; m.w = mu4.w * sc;
      mun4[lane] = m;
    }
    __syncthreads();

    const float4 mm = mun4[lane];
#pragma unroll
    for (int j = 0; j < 4; ++j) {
      const int n = (w << 2) + j;
      const float4 a = hs4[n * 64 + lane];
      float pp = fmaf(a.x, mm.x, fmaf(a.y, mm.y, fmaf(a.z, mm.z, a.w * mm.w)));
      pp = dpp_sum64(pp);
      if (lane == 63) siml[n] = pp;
    }
    __syncthreads();

    const float v = siml[lane];
    const float mx = bmax64(v);
    const float e = expf(v - mx);
    const float s = bsum64(e);
    alpha = e / s;

    mu4 = col_wsum(alpha * hnorm_l);
  }

  if (t < N_PTS) alpha_out[(size_t)b * N_PTS + t] = alpha;
  if (w == 0) ((float4*)(mu_out + (size_t)b * D_DIM))[lane] = mu4;
}

// ---------------------------------------------------------------------------
// Kernel 2: rho MLP via split-bf16 MFMA (x = hi+lo; 3 mfma terms, drop lo*lo).
// 16 batch rows/block, 256 blocks (1/CU), 512 thr = 8 waves.
// Wave w owns N-tiles nt = w*4+j (j=0..3); each 16x16x32 mfma tile:
//   A row = lane&15, C/D col = lane&15, row = (lane>>4)*4+reg  [HW-verified].
// Weights stream as fully-coalesced short8 fragments (1024 B/wave-instr).
// LN1+GELU / LN2 fused via LDS roundtrip with DPP reductions.
// ---------------------------------------------------------------------------
#define APAD 260   // f32 row stride for A LDS (16B-aligned, 2-way banks max)
#define XPAD 516   // f32 row stride for X LDS

__global__ __launch_bounds__(512) void ica_mlp(
    const float* __restrict__ mu_in,
    const unsigned short* __restrict__ bh1, const unsigned short* __restrict__ bl1,
    const unsigned short* __restrict__ bh2, const unsigned short* __restrict__ bl2,
    const float* __restrict__ b1, const float* __restrict__ g1,
    const float* __restrict__ be1, const float* __restrict__ b2,
    const float* __restrict__ g2, const float* __restrict__ be2,
    float* __restrict__ theta) {
  __shared__ float Abuf[16 * APAD];   // 16.6 KB: 16 mu rows
  __shared__ float Xbuf[16 * XPAD];   // 33.0 KB: activations
  const int t = threadIdx.x;
  const int lane = t & 63;
  const int w = t >> 6;               // 0..7
  const int b0 = blockIdx.x * 16;
  const int arow = lane & 15;         // A-fragment row / C col
  const int ag = lane >> 4;           // k-group 0..3

  // ---- stage 16 mu rows (coalesced float4)
  {
#pragma unroll
    for (int s = 0; s < 2; ++s) {
      const int idx = t + 512 * s;
      const int row = idx >> 6, c4 = idx & 63;
      const float4 v = ((const float4*)(mu_in + (size_t)(b0 + row) * D_DIM))[c4];
      *((float4*)(Abuf + row * APAD) + c4) = v;
    }
  }
  __syncthreads();

  // ---- GEMM1: [16x256] @ w1^T -> [16x512]
  short8 ah[8], al[8];
#pragma unroll
  for (int kk = 0; kk < 8; ++kk) {
    const float* base = Abuf + arow * APAD + kk * 32 + ag * 8;
    split8(*(const float4*)base, *(const float4*)(base + 4), ah[kk], al[kk]);
  }
  f32x4 acc[4];
#pragma unroll
  for (int j = 0; j < 4; ++j) acc[j] = (f32x4){0.f, 0.f, 0.f, 0.f};
  {
    const short8* bhv = (const short8*)bh1;
    const short8* blv = (const short8*)bl1;
#pragma unroll
    for (int j = 0; j < 4; ++j) {
      const int nt = w * 4 + j;
#pragma unroll
      for (int kk = 0; kk < 8; ++kk) {
        const short8 bh = bhv[(nt * 8 + kk) * 64 + lane];
        const short8 bl = blv[(nt * 8 + kk) * 64 + lane];
        acc[j] = __builtin_amdgcn_mfma_f32_16x16x32_bf16(ah[kk], bh, acc[j], 0, 0, 0);
        acc[j] = __builtin_amdgcn_mfma_f32_16x16x32_bf16(ah[kk], bl, acc[j], 0, 0, 0);
        acc[j] = __builtin_amdgcn_mfma_f32_16x16x32_bf16(al[kk], bh, acc[j], 0, 0, 0);
      }
    }
  }
  // write X = acc + b1 (C layout: col=lane&15, row=(lane>>4)*4+q)
#pragma unroll
  for (int j = 0; j < 4; ++j) {
    const int col = (w * 4 + j) * 16 + arow;
    const float bb = b1[col];
#pragma unroll
    for (int q = 0; q < 4; ++q)
      Xbuf[(ag * 4 + q) * XPAD + col] = acc[j][q] + bb;
  }
  __syncthreads();

  // ---- LN1 + exact GELU (wave w -> rows w, w+8)
#pragma unroll
  for (int qq = 0; qq < 2; ++qq) {
    const int r = w + 8 * qq;
    float v[8];
#pragma unroll
    for (int kk = 0; kk < 8; ++kk) v[kk] = Xbuf[r * XPAD + lane + 64 * kk];
    float s = 0.f;
#pragma unroll
    for (int kk = 0; kk < 8; ++kk) s += v[kk];
    const float mean = bsum64(s) * (1.0f / 512.0f);
    float vs = 0.f;
#pragma unroll
    for (int kk = 0; kk < 8; ++kk) { const float d = v[kk] - mean; vs = fmaf(d, d, vs); }
    const float rstd = 1.0f / sqrtf(bsum64(vs) * (1.0f / 512.0f) + LN_EPS);
#pragma unroll
    for (int kk = 0; kk < 8; ++kk) {
      const int jx = lane + 64 * kk;
      const float y = (v[kk] - mean) * rstd * g1[jx] + be1[jx];
      Xbuf[r * XPAD + jx] = 0.5f * y * (1.0f + erff(y * 0.70710678118654752f));
    }
  }
  __syncthreads();

  // ---- GEMM2: [16x512] @ w2^T -> [16x512], K in two halves of 8 k-steps
  f32x4 acc2[4];
#pragma unroll
  for (int j = 0; j < 4; ++j) acc2[j] = (f32x4){0.f, 0.f, 0.f, 0.f};
  {
    const short8* bhv = (const short8*)bh2;
    const short8* blv = (const short8*)bl2;
    for (int hh = 0; hh < 2; ++hh) {
#pragma unroll
      for (int kk = 0; kk < 8; ++kk) {
        const float* base = Xbuf + arow * XPAD + (hh * 8 + kk) * 32 + ag * 8;
        split8(*(const float4*)base, *(const float4*)(base + 4), ah[kk], al[kk]);
      }
#pragma unroll
      for (int j = 0; j < 4; ++j) {
        const int nt = w * 4 + j;
#pragma unroll
        for (int kk = 0; kk < 8; ++kk) {
          const int kidx = hh * 8 + kk;
          const short8 bh = bhv[(nt * 16 + kidx) * 64 + lane];
          const short8 bl = blv[(nt * 16 + kidx) * 64 + lane];
          acc2[j] = __builtin_amdgcn_mfma_f32_16x16x32_bf16(ah[kk], bh, acc2[j], 0, 0, 0);
          acc2[j] = __builtin_amdgcn_mfma_f32_16x16x32_bf16(ah[kk], bl, acc2[j], 0, 0, 0);
          acc2[j] = __builtin_amdgcn_mfma_f32_16x16x32_bf16(al[kk], bh, acc2[j], 0, 0, 0);
        }
      }
    }
  }
  __syncthreads();   // all X reads (A-frags) complete before overwrite
#pragma unroll
  for (int j = 0; j < 4; ++j) {
    const int col = (w * 4 + j) * 16 + arow;
    const float bb = b2[col];
#pragma unroll
    for (int q = 0; q < 4; ++q)
      Xbuf[(ag * 4 + q) * XPAD + col] = acc2[j][q] + bb;
  }
  __syncthreads();

  // ---- LN2 + store theta (wave w -> rows w, w+8)
#pragma unroll
  for (int qq = 0; qq < 2; ++qq) {
    const int r = w + 8 * qq;
    float v[8];
#pragma unroll
    for (int kk = 0; kk < 8; ++kk) v[kk] = Xbuf[r * XPAD + lane + 64 * kk];
    float s = 0.f;
#pragma unroll
    for (int kk = 0; kk < 8; ++kk) s += v[kk];
    const float mean = bsum64(s) * (1.0f / 512.0f);
    float vs = 0.f;
#pragma unroll
    for (int kk = 0; kk < 8; ++kk) { const float d = v[kk] - mean; vs = fmaf(d, d, vs); }
    const float rstd = 1.0f / sqrtf(bsum64(vs) * (1.0f / 512.0f) + LN_EPS);
#pragma unroll
    for (int kk = 0; kk < 8; ++kk) {
      const int jx = lane + 64 * kk;
      theta[(size_t)(b0 + r) * OUT_DIM + jx] = (v[kk] - mean) * rstd * g2[jx] + be2[jx];
    }
  }
}

// ---------------------------------------------------------------------------
extern "C" void kernel_launch(void* const* d_in, const int* in_sizes, int n_in,
                              void* d_out, int out_size, void* d_ws, size_t ws_size,
                              hipStream_t stream) {
  const float* h       = (const float*)d_in[0];
  const float* log_tau = (const float*)d_in[1];
  const float* w1      = (const float*)d_in[2];
  const float* b1      = (const float*)d_in[3];
  const float* g1      = (const float*)d_in[4];
  const float* be1     = (const float*)d_in[5];
  const float* w2      = (const float*)d_in[6];
  const float* b2      = (const float*)d_in[7];
  const float* g2      = (const float*)d_in[8];
  const float* be2     = (const float*)d_in[9];

  float* out   = (float*)d_out;
  float* theta = out;                                 // [B, 512]
  float* alpha = out + (size_t)B_TOT * OUT_DIM;       // [B, 64]
  float* mu    = alpha + (size_t)B_TOT * N_PTS;       // [B, 256]

  unsigned short* bh1 = (unsigned short*)d_ws;        // 131072 ushort
  unsigned short* bl1 = bh1 + OUT_DIM * D_DIM;        // 131072
  unsigned short* bh2 = bl1 + OUT_DIM * D_DIM;        // 262144
  unsigned short* bl2 = bh2 + OUT_DIM * OUT_DIM;      // 262144  (1.5 MB total)

  pack_weights<<<1024, 256, 0, stream>>>(w1, w2, bh1, bl1, bh2, bl2);
  ica_cluster<<<B_TOT, 1024, 0, stream>>>(h, log_tau, alpha, mu);
  ica_mlp<<<B_TOT / 16, 512, 0, stream>>>(mu, bh1, bl1, bh2, bl2,
                                          b1, g1, be1, b2, g2, be2, theta);
}